// Round 20
// baseline (524.538 us; speedup 1.0000x reference)
//
#include <hip/hip_runtime.h>
#include <cstdint>
#include <cstddef>

#define S_LEN 97
#define B_DIM 256
#define W_DIM 1024
#define NH    16
#define HDIM  64
#define MROWS (S_LEN * B_DIM)   // 24832 = 97*256

typedef unsigned short u16;
typedef __bf16 bf16x8 __attribute__((ext_vector_type(8)));
typedef float  f32x4  __attribute__((ext_vector_type(4)));

__device__ __forceinline__ u16 f2bf(float f) {
  __bf16 b = (__bf16)f;
  return __builtin_bit_cast(unsigned short, b);
}

// async global->LDS, 16B per lane. LDS dest must be wave-uniform base; HW adds lane*16.
__device__ __forceinline__ void gload16(const void* g, void* lds) {
  __builtin_amdgcn_global_load_lds(
      (const __attribute__((address_space(1))) void*)(uintptr_t)g,
      (__attribute__((address_space(3))) void*)(uint32_t)(uintptr_t)lds,
      16, 0, 0);
}

// ---------------- mega prep kernel (R18/R19-verified) ----------------
__global__ void k_prep(const float* __restrict__ tensor, u16* __restrict__ Xbf,
                       const float* __restrict__ q_w, const float* __restrict__ k_w,
                       const float* __restrict__ in_proj_w, const float* __restrict__ out_w,
                       u16* __restrict__ WC1, u16* __restrict__ W2, u16* __restrict__ WO,
                       const float* __restrict__ v_w, u16* __restrict__ WvT,
                       const float* __restrict__ mha_w, u16* __restrict__ WmT,
                       const float* __restrict__ v_b, const float* __restrict__ in_proj_b,
                       float* __restrict__ bvf,
                       const float* __restrict__ mha_b, const float* __restrict__ out_b,
                       float* __restrict__ bff,
                       float* __restrict__ tab, const float* __restrict__ mask,
                       float* __restrict__ maskP, const float* __restrict__ q_b,
                       const float* __restrict__ k_b, float* __restrict__ bc1,
                       float* __restrict__ zb) {
  __shared__ float tlds[32][33];
  const int blk = blockIdx.x, t = threadIdx.x;

  if (blk < 24832) {
    const int i = blk * 256 + t;
    float4 v = ((const float4*)tensor)[i];
    uint2 pk;
    pk.x = (uint32_t)f2bf(v.x) | ((uint32_t)f2bf(v.y) << 16);
    pk.y = (uint32_t)f2bf(v.z) | ((uint32_t)f2bf(v.w) << 16);
    ((uint2*)Xbf)[i] = pk;
  } else if (blk < 30976) {
    const int i = (blk - 24832) * 256 + t;
    const float* s; u16* d; int off;
    if (i < 262144)        { s = q_w;       d = WC1;           off = i; }
    else if (i < 524288)   { s = k_w;       d = WC1 + 1048576; off = i - 262144; }
    else if (i < 1310720)  { s = in_proj_w; d = W2;            off = i - 524288; }
    else                   { s = out_w;     d = WO;            off = i - 1310720; }
    float4 v = ((const float4*)s)[off];
    uint2 pk;
    pk.x = (uint32_t)f2bf(v.x) | ((uint32_t)f2bf(v.y) << 16);
    pk.y = (uint32_t)f2bf(v.z) | ((uint32_t)f2bf(v.w) << 16);
    ((uint2*)d)[off] = pk;
  } else if (blk < 33024) {
    const int idx = blk - 30976;
    const int z = idx >> 10, rem = idx & 1023;
    const float* src = z ? mha_w : v_w;
    u16* dst = z ? WmT : WvT;
    const int bx = (rem & 31) * 32, by = (rem >> 5) * 32;
    const int tx = t & 31, ty = t >> 5;   // 32 x 8
    for (int yy = ty; yy < 32; yy += 8)
      tlds[yy][tx] = src[(size_t)(by + yy) * 1024 + bx + tx];
    __syncthreads();
    for (int yy = ty; yy < 32; yy += 8)
      dst[(size_t)(bx + yy) * 1024 + by + tx] = f2bf(tlds[tx][yy]);
  } else if (blk < 33536) {
    const int bb = blk - 33024;
    const int lane = t & 63, wave = t >> 6;
    const float* M; const float* v; const float* b2; float* out; int rb;
    if (bb < 256) { M = in_proj_w + (size_t)2048 * 1024; v = v_b; b2 = in_proj_b + 2048; out = bvf; rb = bb * 4; }
    else          { M = out_w; v = mha_b; b2 = out_b; out = bff; rb = (bb - 256) * 4; }
    const int row = rb + wave;
    float s = 0.f;
    for (int k = lane; k < 1024; k += 64) s += M[(size_t)row * 1024 + k] * v[k];
#pragma unroll
    for (int d = 32; d; d >>= 1) s += __shfl_xor(s, d);
    if (lane == 0) out[row] = s + b2[row];
  } else {
    const int bb = blk - 33536;
    if (bb < 194) {
      const int idx = bb * 256 + t;
      if (idx < S_LEN * 512) {
        const int s = idx / 512, i = idx % 512;
        const float freq = expf(-(float)i * (9.210340371976184f / 512.0f));
        float sv, cv;
        sincosf((float)s * freq, &sv, &cv);
        tab[idx * 2 + 0] = cv;
        tab[idx * 2 + 1] = sv;
      }
    } else if (bb < 258) {
      const int i = (bb - 194) * 256 + t;     // 16384
      const int r = i >> 7, c = i & 127;
      float v;
      if (c >= S_LEN) v = -1e30f;
      else if (r < S_LEN) v = mask[r * S_LEN + c];
      else v = 0.f;
      maskP[i] = v;
    } else if (bb < 266) {
      const int i = (bb - 258) * 256 + t;     // 2048
      bc1[i] = (i < W_DIM) ? q_b[i] : k_b[i - W_DIM];
    } else {
      const int i = (bb - 266) * 256 + t;     // 1024
      zb[i] = 0.f;
    }
  }
}

// ---------------- small 128x128 GEMM: both weight folds in one launch ----------------
__global__ __launch_bounds__(256) void k_gemmfold(
    const u16* __restrict__ A0, const u16* __restrict__ B0, u16* __restrict__ C0,
    const u16* __restrict__ A1, const u16* __restrict__ B1, u16* __restrict__ C1,
    const float* __restrict__ zb) {
  __shared__ u16 As[128 * 64];
  __shared__ u16 Bs[128 * 64];

  const u16* A = blockIdx.z ? A1 : A0;
  const u16* Bw = blockIdx.z ? B1 : B0;
  u16* Cp = blockIdx.z ? C1 : C0;

  const int tid = threadIdx.x, lane = tid & 63, wave = tid >> 6;
  const int wm = wave >> 1, wn = wave & 1;
  const int m0 = blockIdx.y * 128;
  const int n0 = blockIdx.x * 128;

  f32x4 acc[4][4] = {};

  const int lrow = lane >> 3;
  const int lcol = (lane & 7) * 8;
  const u16* Ag = A + (size_t)(m0 + wave * 8 + lrow) * 1024 + lcol;
  const u16* Bg = Bw + (size_t)(n0 + wave * 8 + lrow) * 1024 + lcol;
  u16* Asl = As + wave * 8 * 64;
  u16* Bsl = Bs + wave * 8 * 64;

  for (int kt = 0; kt < 1024; kt += 64) {
#pragma unroll
    for (int i = 0; i < 4; ++i) {
      gload16(Ag + (size_t)(i * 32) * 1024 + kt, Asl + i * 2048);
      gload16(Bg + (size_t)(i * 32) * 1024 + kt, Bsl + i * 2048);
    }
    __syncthreads();
#pragma unroll
    for (int kk = 0; kk < 2; ++kk) {
      bf16x8 af[4], bfr[4];
#pragma unroll
      for (int m = 0; m < 4; ++m)
        af[m] = *(const bf16x8*)(As + (wm * 64 + m * 16 + (lane & 15)) * 64 + kk * 32 + (lane >> 4) * 8);
#pragma unroll
      for (int n = 0; n < 4; ++n)
        bfr[n] = *(const bf16x8*)(Bs + (wn * 64 + n * 16 + (lane & 15)) * 64 + kk * 32 + (lane >> 4) * 8);
#pragma unroll
      for (int m = 0; m < 4; ++m)
#pragma unroll
        for (int n = 0; n < 4; ++n)
          acc[m][n] = __builtin_amdgcn_mfma_f32_16x16x32_bf16(af[m], bfr[n], acc[m][n], 0, 0, 0);
    }
    __syncthreads();
  }

  const int r0 = (lane >> 4) * 4;
  const int c0 = lane & 15;
#pragma unroll
  for (int m = 0; m < 4; ++m)
#pragma unroll
    for (int n = 0; n < 4; ++n) {
      const int col = n0 + wn * 64 + n * 16 + c0;
#pragma unroll
      for (int r = 0; r < 4; ++r) {
        const int row = m0 + wm * 64 + m * 16 + r0 + r;
        Cp[(size_t)row * 1024 + col] = f2bf(acc[m][n][r] + zb[col]);
      }
    }
}

// ---------------- 128x256 GEMM (R17/R19-verified) — MODE 0 only ----------------
template <int MODE>
__global__ __launch_bounds__(512, 4) void k_gemm256(
    const u16* __restrict__ A, int lda,
    const u16* __restrict__ BwA, const u16* __restrict__ BwB,
    const float* __restrict__ biasA, const float* __restrict__ biasB,
    void* __restrict__ CpA, void* __restrict__ CpB, int ldc,
    size_t thirdStride, const float* __restrict__ tab, int Nt, int NtA) {
  __shared__ u16 lds[3 * 12288];  // 72KB -> 2 blocks/CU

  const int tid = threadIdx.x, lane = tid & 63, wave = tid >> 6;
  const int wm = wave >> 2, wn = wave & 3;
  const int c0 = lane & 15, hi = lane >> 4;

  const int nwg = gridDim.x;
  const int qq = nwg >> 3, rr_ = nwg & 7;
  const int xcd = blockIdx.x & 7, sub = blockIdx.x >> 3;
  const int seq = (xcd < rr_ ? xcd * (qq + 1) : rr_ * (qq + 1) + (xcd - rr_) * qq) + sub;
  const int mt = seq / Nt, ntRaw = seq - mt * Nt;
  const int m0 = mt * 128;
  bool isV = false;
  int n0 = ntRaw * 256;
  const u16* Bbase;
  const float* bias;
  if (ntRaw >= NtA) {
    isV = true;
    n0 = (ntRaw - NtA) * 256;
    Bbase = BwB + (size_t)n0 * 1024;
    bias = biasB;
  } else {
    Bbase = BwA + (size_t)n0 * 1024;
    bias = biasA;
  }

  const int Lb = tid >> 3, pc = tid & 7;
  const int lcl = pc ^ (Lb & 7);
  const int rsel = lcl >> 2;
  const int csel = (lcl & 3) * 8;
  const u16* aS = A + (size_t)(m0 + Lb + 64 * rsel) * lda + csel;
  const u16* bS0 = Bbase + (size_t)(Lb + 128 * rsel) * 1024 + csel;
  const u16* bS1 = Bbase + (size_t)(64 + Lb + 128 * rsel) * 1024 + csel;
  const uint32_t ldsW = wave * 512;

  auto stage = [&](int tt, u16* slot) {
    gload16(aS + tt * 32, slot + ldsW);
    gload16(bS0 + tt * 32, slot + 4096 + ldsW);
    gload16(bS1 + tt * 32, slot + 8192 + ldsW);
  };

  int aofr[4], bofr[4];
#pragma unroll
  for (int m = 0; m < 4; ++m)
    aofr[m] = (m * 16 + c0) * 64 + ((((wm << 2) | hi) ^ (c0 & 7)) * 8);
#pragma unroll
  for (int n = 0; n < 4; ++n)
    bofr[n] = 4096 + ((wn & 1) * 64 + n * 16 + c0) * 64 +
              (((((wn >> 1) << 2) | hi) ^ (c0 & 7)) * 8);

  u16* s0 = lds;
  u16* s1 = lds + 12288;
  u16* s2 = lds + 24576;

  stage(0, s0); stage(1, s1);
  asm volatile("s_waitcnt vmcnt(3)" ::: "memory");
  __builtin_amdgcn_s_barrier();
  __builtin_amdgcn_sched_barrier(0);

  f32x4 acc[4][4] = {};

  for (int t = 0; t < 32; ++t) {
    bf16x8 af[4], bfr[4];
#pragma unroll
    for (int n = 0; n < 4; ++n) bfr[n] = *(const bf16x8*)(s0 + bofr[n]);
#pragma unroll
    for (int m = 0; m < 4; ++m) af[m] = *(const bf16x8*)(s0 + aofr[m]);
    if (t + 2 < 32) stage(t + 2, s2);
    __builtin_amdgcn_s_setprio(1);
#pragma unroll
    for (int m = 0; m < 4; ++m)
#pragma unroll
      for (int n = 0; n < 4; ++n)
        acc[m][n] = __builtin_amdgcn_mfma_f32_16x16x32_bf16(af[m], bfr[n], acc[m][n], 0, 0, 0);
    __builtin_amdgcn_s_setprio(0);
    if (t < 31) {
      if (t < 30) asm volatile("s_waitcnt vmcnt(3)" ::: "memory");
      else        asm volatile("s_waitcnt vmcnt(0)" ::: "memory");
      __builtin_amdgcn_s_barrier();
      __builtin_amdgcn_sched_barrier(0);
      u16* tmp = s0; s0 = s1; s1 = s2; s2 = tmp;
    }
  }

  const int r0 = (lane >> 4) * 4;
#pragma unroll
  for (int m = 0; m < 4; ++m) {
#pragma unroll
    for (int n = 0; n < 4; ++n) {
      const int col = n0 + wn * 64 + n * 16 + c0;
      const float bv = bias[col];
      if (!isV) {
        const int pairI = (col & 1023) >> 1;
        const float sgn = (col & 1) ? 1.f : -1.f;
#pragma unroll
        for (int r = 0; r < 4; ++r) {
          const int row = m0 + wm * 64 + m * 16 + r0 + r;
          const float v = acc[m][n][r] + bv;
          const float p = __shfl_xor(v, 1);
          const float2 cs = ((const float2*)tab)[(row >> 8) * 512 + pairI];
          ((u16*)CpA)[(size_t)row * ldc + col] = f2bf(v * cs.x + sgn * p * cs.y);
        }
      } else {
        const int h = (col >> 6) & 15, d = col & 63;
#pragma unroll
        for (int r = 0; r < 4; ++r) {
          const int row = m0 + wm * 64 + m * 16 + r0 + r;
          const int s = row >> 8, b = row & 255;
          ((u16*)CpB)[(((size_t)(b * NH + h) * S_LEN + s) * HDIM + d)] =
              f2bf(acc[m][n][r] + bv);
        }
      }
    }
  }
}

// ---------------- 128x128 GEMM, 3-slot 48KB LDS, target 3 blocks/CU ----------------
// Per-wave 64x32 (acc[4][2]=32 VGPR, est total ~80 <= 85 cap at (512,6)).
// Same packed chunk-XOR swizzle family; 2 loads/tile -> boundary vmcnt(2).
// MODE 1: GEMM2 q/k head-scatter (Nt=16); MODE 2: f32 row-major out (Nt=8).
template <int MODE>
__global__ __launch_bounds__(512, 6) void k_gemm128(
    const u16* __restrict__ A, int lda, const u16* __restrict__ Bw,
    const float* __restrict__ bias, void* __restrict__ Cp, int ldc,
    size_t thirdStride, int Nt) {
  __shared__ u16 lds[3 * 8192];  // 3 x 16KB = 48KB -> 3 blocks/CU

  const int tid = threadIdx.x, lane = tid & 63, wave = tid >> 6;
  const int wm = wave >> 2, wn = wave & 3;
  const int c0 = lane & 15, hi = lane >> 4;

  const int nwg = gridDim.x;
  const int qq = nwg >> 3, rr_ = nwg & 7;
  const int xcd = blockIdx.x & 7, sub = blockIdx.x >> 3;
  const int seq = (xcd < rr_ ? xcd * (qq + 1) : rr_ * (qq + 1) + (xcd - rr_) * qq) + sub;
  const int mt = seq / Nt, ntRaw = seq - mt * Nt;
  const int m0 = mt * 128;
  const int n0 = ntRaw * 128;
  const u16* Bbase = Bw + (size_t)n0 * 1024;
  const int aoff = (MODE == 1) ? (n0 & ~1023) : 0;

  // staging: A[128][32]->[64][64] packed, B[128][32]->[64][64] packed; 1 load each
  const int Lb = tid >> 3, pc = tid & 7;
  const int lcl = pc ^ (Lb & 7);
  const int rsel = lcl >> 2;
  const int csel = (lcl & 3) * 8;
  const u16* aS = A + (size_t)(m0 + Lb + 64 * rsel) * lda + aoff + csel;
  const u16* bS = Bbase + (size_t)(Lb + 64 * rsel) * 1024 + csel;
  const uint32_t ldsW = wave * 512;

  auto stage = [&](int tt, u16* slot) {
    gload16(aS + tt * 32, slot + ldsW);
    gload16(bS + tt * 32, slot + 4096 + ldsW);
  };

  // fragment read offsets
  int aofr[4], bofr[2];
#pragma unroll
  for (int m = 0; m < 4; ++m)
    aofr[m] = (m * 16 + c0) * 64 + ((((wm << 2) | hi) ^ (c0 & 7)) * 8);
#pragma unroll
  for (int n = 0; n < 2; ++n)
    bofr[n] = 4096 + ((wn & 1) * 32 + n * 16 + c0) * 64 +
              (((((wn >> 1) << 2) | hi) ^ (c0 & 7)) * 8);

  u16* s0 = lds;
  u16* s1 = lds + 8192;
  u16* s2 = lds + 16384;

  stage(0, s0); stage(1, s1);
  asm volatile("s_waitcnt vmcnt(2)" ::: "memory");
  __builtin_amdgcn_s_barrier();
  __builtin_amdgcn_sched_barrier(0);

  f32x4 acc[4][2] = {};

  for (int t = 0; t < 32; ++t) {
    bf16x8 af[4], bfr[2];
#pragma unroll
    for (int n = 0; n < 2; ++n) bfr[n] = *(const bf16x8*)(s0 + bofr[n]);
#pragma unroll
    for (int m = 0; m < 4; ++m) af[m] = *(const bf16x8*)(s0 + aofr[m]);
    if (t + 2 < 32) stage(t + 2, s2);
    __builtin_amdgcn_s_setprio(1);
#pragma unroll
    for (int m = 0; m < 4; ++m)
#pragma unroll
      for (int n = 0; n < 2; ++n)
        acc[m][n] = __builtin_amdgcn_mfma_f32_16x16x32_bf16(af[m], bfr[n], acc[m][n], 0, 0, 0);
    __builtin_amdgcn_s_setprio(0);
    if (t < 31) {
      if (t < 30) asm volatile("s_waitcnt vmcnt(2)" ::: "memory");
      else        asm volatile("s_waitcnt vmcnt(0)" ::: "memory");
      __builtin_amdgcn_s_barrier();
      __builtin_amdgcn_sched_barrier(0);
      u16* tmp = s0; s0 = s1; s1 = s2; s2 = tmp;
    }
  }

  const int r0 = (lane >> 4) * 4;
#pragma unroll
  for (int m = 0; m < 4; ++m) {
#pragma unroll
    for (int n = 0; n < 2; ++n) {
      const int col = n0 + wn * 32 + n * 16 + c0;
      const float bv = bias[col];
      if (MODE == 1) {
        const int which = col >> 10, c = col & 1023;
        const int h = c >> 6, d = c & 63;
        const float sc = (which == 0) ? 0.125f : 1.0f;
#pragma unroll
        for (int r = 0; r < 4; ++r) {
          const int row = m0 + wm * 64 + m * 16 + r0 + r;
          const int s = row >> 8, b = row & 255;
          ((u16*)Cp)[(size_t)which * thirdStride +
                     (((size_t)(b * NH + h) * S_LEN + s) * HDIM + d)] =
              f2bf((acc[m][n][r] + bv) * sc);
        }
      } else {
#pragma unroll
        for (int r = 0; r < 4; ++r) {
          const int row = m0 + wm * 64 + m * 16 + r0 + r;
          ((float*)Cp)[(size_t)row * ldc + col] = acc[m][n][r] + bv;
        }
      }
    }
  }
}

// ---------------- attention v6 (R14/R16/R19-verified) ----------------
__global__ __launch_bounds__(512, 4) void k_attn(const u16* __restrict__ qkv2,
                                                 const float* __restrict__ maskP,
                                                 u16* __restrict__ O1) {
  __shared__ u16 Vt[66 * 128];     // Vt[d][s ^ ((d&7)<<3)]; row 64 = ones  16.5KB
  __shared__ u16 Pb[128 * 128];    // Pb[q][s ^ ((q&7)<<3)]; reused as Ob   32KB
  __shared__ float redS[128];

  const size_t TS = (size_t)MROWS * W_DIM;
  const int bh = blockIdx.x, b = bh >> 4, h = bh & 15;
  const int tid = threadIdx.x, lane = tid & 63, wave = tid >> 6;
  const int wm = wave >> 2;
  const int wn = wave & 3;
  const int c0 = lane & 15, hi = lane >> 4;

  const u16* Qg = qkv2 + (size_t)bh * (S_LEN * HDIM);
  const u16* Kg = Qg + TS;
  const u16* Vg = Qg + 2 * TS;

  float mk[4][2][4];
#pragma unroll
  for (int m = 0; m < 4; ++m)
#pragma unroll
    for (int n = 0; n < 2; ++n)
#pragma unroll
      for (int r = 0; r < 4; ++r)
        mk[m][n][r] = maskP[(wm * 64 + m * 16 + hi * 4 + r) * 128 + wn * 32 + n * 16 + c0];

  for (int idx = tid; idx < 1024; idx += 512) {
    const int s = idx >> 3, c = (idx & 7) * 8;
    uint4 vv = make_uint4(0, 0, 0, 0);
    if (s < S_LEN) vv = *(const uint4*)(Vg + (size_t)s * HDIM + c);
    u16 tmp[8];
    *(uint4*)tmp = vv;
#pragma unroll
    for (int j = 0; j < 8; ++j)
      Vt[(c + j) * 128 + (s ^ (j << 3))] = tmp[j];
  }
  if (tid < 128) Vt[64 * 128 + tid] = 0x3F80;   // ones row (d=64, swz=0)

  f32x4 acc[4][2] = {};
#pragma unroll
  for (int kk = 0; kk < 2; ++kk) {
    bf16x8 af[4], bfr[2];
#pragma unroll
    for (int m = 0; m < 4; ++m)
      af[m] = *(const bf16x8*)(Qg + (size_t)(wm * 64 + m * 16 + c0) * HDIM + kk * 32 + hi * 8);
#pragma unroll
    for (int n = 0; n < 2; ++n)
      bfr[n] = *(const bf16x8*)(Kg + (size_t)(wn * 32 + n * 16 + c0) * HDIM + kk * 32 + hi * 8);
#pragma unroll
    for (int m = 0; m < 4; ++m)
#pragma unroll
      for (int n = 0; n < 2; ++n)
        acc[m][n] = __builtin_amdgcn_mfma_f32_16x16x32_bf16(af[m], bfr[n], acc[m][n], 0, 0, 0);
  }

#pragma unroll
  for (int m = 0; m < 4; ++m) {
#pragma unroll
    for (int r = 0; r < 4; ++r) {
      const int row = wm * 64 + m * 16 + hi * 4 + r;
#pragma unroll
      for (int n = 0; n < 2; ++n) {
        const int col = wn * 32 + n * 16 + c0;
        const float e = __expf(acc[m][n][r] + mk[m][n][r]);
        Pb[row * 128 + (col ^ ((row & 7) << 3))] = f2bf(e);
      }
    }
  }
  __syncthreads();

  f32x4 o[4] = {};
  f32x4 osum[4] = {};
#pragma unroll
  for (int kk = 0; kk < 4; ++kk) {
    bf16x8 pa[4], vb, vbs;
#pragma unroll
    for (int m = 0; m < 4; ++m) {
      const int row = wm * 64 + m * 16 + c0;
      pa[m] = *(const bf16x8*)(Pb + row * 128 + ((kk * 32 + hi * 8) ^ ((row & 7) << 3)));
    }
    {
      const int d = wn * 16 + c0;
      vb = *(const bf16x8*)(Vt + d * 128 + ((kk * 32 + hi * 8) ^ ((d & 7) << 3)));
    }
    if (wn == 0)
      vbs = *(const bf16x8*)(Vt + 64 * 128 + (kk * 32 + hi * 8));  // broadcast
#pragma unroll
    for (int m = 0; m < 4; ++m)
      o[m] = __builtin_amdgcn_mfma_f32_16x16x32_bf16(pa[m], vb, o[m], 0, 0, 0);
    if (wn == 0) {
#pragma unroll
      for (int m = 0; m < 4; ++m)
        osum[m] = __builtin_amdgcn_mfma_f32_16x16x32_bf16(pa[m], vbs, osum[m], 0, 0, 0);
    }
  }

  if (wn == 0 && c0 == 0) {
#pragma unroll
    for (int m = 0; m < 4; ++m)
#pragma unroll
      for (int r = 0; r < 4; ++r)
        redS[wm * 64 + m * 16 + hi * 4 + r] = osum[m][r];
  }
  __syncthreads();

  u16* Ob = Pb;
#pragma unroll
  for (int m = 0; m < 4; ++m)
#pragma unroll
    for (int r = 0; r < 4; ++r) {
      const int row = wm * 64 + m * 16 + hi * 4 + r;
      const float iv = 1.0f / redS[row];
      Ob[row * 80 + wn * 16 + c0] = f2bf(o[m][r] * iv);
    }
  __syncthreads();

  if (tid < 4 * S_LEN) {
    const int row = tid >> 2, q = tid & 3;
    const u16* src = Ob + row * 80 + q * 16;
    uint4 a0 = *(const uint4*)(src);
    uint4 a1 = *(const uint4*)(src + 8);
    u16* dst = O1 + ((size_t)row * B_DIM + b) * W_DIM + h * HDIM + q * 16;
    *(uint4*)dst = a0;
    *(uint4*)(dst + 8) = a1;
  }
}

// ---------------- launcher ----------------
extern "C" void kernel_launch(void* const* d_in, const int* in_sizes, int n_in,
                              void* d_out, int out_size, void* d_ws, size_t ws_size,
                              hipStream_t stream) {
  (void)in_sizes; (void)n_in; (void)out_size; (void)ws_size;
  const float* tensor    = (const float*)d_in[0];
  const float* mask      = (const float*)d_in[1];
  const float* q_w       = (const float*)d_in[2];
  const float* q_b       = (const float*)d_in[3];
  const float* k_w       = (const float*)d_in[4];
  const float* k_b       = (const float*)d_in[5];
  const float* v_w       = (const float*)d_in[6];
  const float* v_b       = (const float*)d_in[7];
  const float* in_proj_w = (const float*)d_in[8];
  const float* in_proj_b = (const float*)d_in[9];
  const float* mha_w     = (const float*)d_in[10];
  const float* mha_b     = (const float*)d_in[11];
  const float* out_w     = (const float*)d_in[12];
  const float* out_b     = (const float*)d_in[13];

  char* ws = (char*)d_ws;
  size_t off = 0;
  auto alloc = [&](size_t bytes) {
    char* p = ws + off;
    off += (bytes + 255) & ~(size_t)255;
    return p;
  };

  const size_t TS = (size_t)MROWS * W_DIM;

  float* tab = (float*)alloc((size_t)S_LEN * 512 * 2 * sizeof(float));
  float* maskP = (float*)alloc((size_t)128 * 128 * sizeof(float));
  u16* Xbf   = (u16*)alloc(TS * 2);                          // reused as O1
  u16* qkv1  = (u16*)alloc((size_t)MROWS * 2048 * 2);        // q,k after GEMM1+rope
  u16* qkv2  = (u16*)alloc(TS * 3 * 2);                      // q,k,v head layout
  u16* WC1   = (u16*)alloc((size_t)2048 * 1024 * 2);         // [q_w;k_w] bf16
  u16* W2    = (u16*)alloc((size_t)3072 * 1024 * 2);         // in_proj bf16
  u16* WvT   = (u16*)alloc((size_t)1024 * 1024 * 2);
  u16* WmT   = (u16*)alloc((size_t)1024 * 1024 * 2);
  u16* WO    = (u16*)alloc((size_t)1024 * 1024 * 2);
  u16* WVf   = (u16*)alloc((size_t)1024 * 1024 * 2);         // Wv2 @ Wv
  u16* WFf   = (u16*)alloc((size_t)1024 * 1024 * 2);         // Wo @ Wm
  float* bc1 = (float*)alloc(2048 * sizeof(float));
  float* bvf = (float*)alloc(1024 * sizeof(float));
  float* bff = (float*)alloc(1024 * sizeof(float));
  float* zb  = (float*)alloc(1024 * sizeof(float));
  u16* O1 = Xbf;  // X dead after fused GEMM1v

  // ---- mega prep (one launch) ----
  k_prep<<<dim3(33806), 256, 0, stream>>>(
      tensor, Xbf, q_w, k_w, in_proj_w, out_w, WC1, W2, WO,
      v_w, WvT, mha_w, WmT, v_b, in_proj_b, bvf, mha_b, out_b, bff,
      tab, mask, maskP, q_b, k_b, bc1, zb);

  // ---- weight folds (both in one launch) ----
  k_gemmfold<<<dim3(8, 8, 2), 256, 0, stream>>>(
      W2 + (size_t)2048 * 1024, WvT, WVf, WO, WmT, WFf, zb);

  // ---- fused GEMM1+v: X @ [qk]^T -> qkv1(rope) ; X @ WVf^T -> v heads ----
  k_gemm256<0><<<dim3(194 * 12), 512, 0, stream>>>(
      Xbf, W_DIM, WC1, WVf, bc1, bvf, qkv1, qkv2 + 2 * TS, 2048, TS, tab, 12, 8);

  // ---- GEMM2 (block-diagonal): qkv1 @ [Wq2;Wk2]^T -> q,k heads (q scaled 1/8) ----
  k_gemm128<1><<<dim3(194 * 16), 512, 0, stream>>>(
      qkv1, 2048, W2, in_proj_b, qkv2, 0, TS, 16);

  // ---- attention ----
  k_attn<<<dim3(B_DIM * NH), 512, 0, stream>>>(qkv2, maskP, O1);

  // ---- output (folded): O1 @ WFf^T + bff -> d_out (fp32) ----
  k_gemm128<2><<<dim3(194 * 8), 512, 0, stream>>>(
      O1, W_DIM, WFf, bff, d_out, W_DIM, 0, 8);
}

// Round 21
// 507.847 us; speedup vs baseline: 1.0329x; 1.0329x over previous
//
#include <hip/hip_runtime.h>
#include <cstdint>
#include <cstddef>

#define S_LEN 97
#define B_DIM 256
#define W_DIM 1024
#define NH    16
#define HDIM  64
#define MROWS (S_LEN * B_DIM)   // 24832 = 97*256

typedef unsigned short u16;
typedef __bf16 bf16x8 __attribute__((ext_vector_type(8)));
typedef float  f32x4  __attribute__((ext_vector_type(4)));

__device__ __forceinline__ u16 f2bf(float f) {
  __bf16 b = (__bf16)f;
  return __builtin_bit_cast(unsigned short, b);
}

// async global->LDS, 16B per lane. LDS dest must be wave-uniform base; HW adds lane*16.
__device__ __forceinline__ void gload16(const void* g, void* lds) {
  __builtin_amdgcn_global_load_lds(
      (const __attribute__((address_space(1))) void*)(uintptr_t)g,
      (__attribute__((address_space(3))) void*)(uint32_t)(uintptr_t)lds,
      16, 0, 0);
}

// ---------------- mega prep kernel (R18/R19-verified) ----------------
__global__ void k_prep(const float* __restrict__ tensor, u16* __restrict__ Xbf,
                       const float* __restrict__ q_w, const float* __restrict__ k_w,
                       const float* __restrict__ in_proj_w, const float* __restrict__ out_w,
                       u16* __restrict__ WC1, u16* __restrict__ W2, u16* __restrict__ WO,
                       const float* __restrict__ v_w, u16* __restrict__ WvT,
                       const float* __restrict__ mha_w, u16* __restrict__ WmT,
                       const float* __restrict__ v_b, const float* __restrict__ in_proj_b,
                       float* __restrict__ bvf,
                       const float* __restrict__ mha_b, const float* __restrict__ out_b,
                       float* __restrict__ bff,
                       float* __restrict__ tab, const float* __restrict__ mask,
                       float* __restrict__ maskP, const float* __restrict__ q_b,
                       const float* __restrict__ k_b, float* __restrict__ bc1,
                       float* __restrict__ zb) {
  __shared__ float tlds[32][33];
  const int blk = blockIdx.x, t = threadIdx.x;

  if (blk < 24832) {
    const int i = blk * 256 + t;
    float4 v = ((const float4*)tensor)[i];
    uint2 pk;
    pk.x = (uint32_t)f2bf(v.x) | ((uint32_t)f2bf(v.y) << 16);
    pk.y = (uint32_t)f2bf(v.z) | ((uint32_t)f2bf(v.w) << 16);
    ((uint2*)Xbf)[i] = pk;
  } else if (blk < 30976) {
    const int i = (blk - 24832) * 256 + t;
    const float* s; u16* d; int off;
    if (i < 262144)        { s = q_w;       d = WC1;           off = i; }
    else if (i < 524288)   { s = k_w;       d = WC1 + 1048576; off = i - 262144; }
    else if (i < 1310720)  { s = in_proj_w; d = W2;            off = i - 524288; }
    else                   { s = out_w;     d = WO;            off = i - 1310720; }
    float4 v = ((const float4*)s)[off];
    uint2 pk;
    pk.x = (uint32_t)f2bf(v.x) | ((uint32_t)f2bf(v.y) << 16);
    pk.y = (uint32_t)f2bf(v.z) | ((uint32_t)f2bf(v.w) << 16);
    ((uint2*)d)[off] = pk;
  } else if (blk < 33024) {
    const int idx = blk - 30976;
    const int z = idx >> 10, rem = idx & 1023;
    const float* src = z ? mha_w : v_w;
    u16* dst = z ? WmT : WvT;
    const int bx = (rem & 31) * 32, by = (rem >> 5) * 32;
    const int tx = t & 31, ty = t >> 5;   // 32 x 8
    for (int yy = ty; yy < 32; yy += 8)
      tlds[yy][tx] = src[(size_t)(by + yy) * 1024 + bx + tx];
    __syncthreads();
    for (int yy = ty; yy < 32; yy += 8)
      dst[(size_t)(bx + yy) * 1024 + by + tx] = f2bf(tlds[tx][yy]);
  } else if (blk < 33536) {
    const int bb = blk - 33024;
    const int lane = t & 63, wave = t >> 6;
    const float* M; const float* v; const float* b2; float* out; int rb;
    if (bb < 256) { M = in_proj_w + (size_t)2048 * 1024; v = v_b; b2 = in_proj_b + 2048; out = bvf; rb = bb * 4; }
    else          { M = out_w; v = mha_b; b2 = out_b; out = bff; rb = (bb - 256) * 4; }
    const int row = rb + wave;
    float s = 0.f;
    for (int k = lane; k < 1024; k += 64) s += M[(size_t)row * 1024 + k] * v[k];
#pragma unroll
    for (int d = 32; d; d >>= 1) s += __shfl_xor(s, d);
    if (lane == 0) out[row] = s + b2[row];
  } else {
    const int bb = blk - 33536;
    if (bb < 194) {
      const int idx = bb * 256 + t;
      if (idx < S_LEN * 512) {
        const int s = idx / 512, i = idx % 512;
        const float freq = expf(-(float)i * (9.210340371976184f / 512.0f));
        float sv, cv;
        sincosf((float)s * freq, &sv, &cv);
        tab[idx * 2 + 0] = cv;
        tab[idx * 2 + 1] = sv;
      }
    } else if (bb < 258) {
      const int i = (bb - 194) * 256 + t;     // 16384
      const int r = i >> 7, c = i & 127;
      float v;
      if (c >= S_LEN) v = -1e30f;
      else if (r < S_LEN) v = mask[r * S_LEN + c];
      else v = 0.f;
      maskP[i] = v;
    } else if (bb < 266) {
      const int i = (bb - 258) * 256 + t;     // 2048
      bc1[i] = (i < W_DIM) ? q_b[i] : k_b[i - W_DIM];
    } else {
      const int i = (bb - 266) * 256 + t;     // 1024
      zb[i] = 0.f;
    }
  }
}

// ---------------- small 128x128 GEMM: both weight folds in one launch ----------------
__global__ __launch_bounds__(256) void k_gemmfold(
    const u16* __restrict__ A0, const u16* __restrict__ B0, u16* __restrict__ C0,
    const u16* __restrict__ A1, const u16* __restrict__ B1, u16* __restrict__ C1,
    const float* __restrict__ zb) {
  __shared__ u16 As[128 * 64];
  __shared__ u16 Bs[128 * 64];

  const u16* A = blockIdx.z ? A1 : A0;
  const u16* Bw = blockIdx.z ? B1 : B0;
  u16* Cp = blockIdx.z ? C1 : C0;

  const int tid = threadIdx.x, lane = tid & 63, wave = tid >> 6;
  const int wm = wave >> 1, wn = wave & 1;
  const int m0 = blockIdx.y * 128;
  const int n0 = blockIdx.x * 128;

  f32x4 acc[4][4] = {};

  const int lrow = lane >> 3;
  const int lcol = (lane & 7) * 8;
  const u16* Ag = A + (size_t)(m0 + wave * 8 + lrow) * 1024 + lcol;
  const u16* Bg = Bw + (size_t)(n0 + wave * 8 + lrow) * 1024 + lcol;
  u16* Asl = As + wave * 8 * 64;
  u16* Bsl = Bs + wave * 8 * 64;

  for (int kt = 0; kt < 1024; kt += 64) {
#pragma unroll
    for (int i = 0; i < 4; ++i) {
      gload16(Ag + (size_t)(i * 32) * 1024 + kt, Asl + i * 2048);
      gload16(Bg + (size_t)(i * 32) * 1024 + kt, Bsl + i * 2048);
    }
    __syncthreads();
#pragma unroll
    for (int kk = 0; kk < 2; ++kk) {
      bf16x8 af[4], bfr[4];
#pragma unroll
      for (int m = 0; m < 4; ++m)
        af[m] = *(const bf16x8*)(As + (wm * 64 + m * 16 + (lane & 15)) * 64 + kk * 32 + (lane >> 4) * 8);
#pragma unroll
      for (int n = 0; n < 4; ++n)
        bfr[n] = *(const bf16x8*)(Bs + (wn * 64 + n * 16 + (lane & 15)) * 64 + kk * 32 + (lane >> 4) * 8);
#pragma unroll
      for (int m = 0; m < 4; ++m)
#pragma unroll
        for (int n = 0; n < 4; ++n)
          acc[m][n] = __builtin_amdgcn_mfma_f32_16x16x32_bf16(af[m], bfr[n], acc[m][n], 0, 0, 0);
    }
    __syncthreads();
  }

  const int r0 = (lane >> 4) * 4;
  const int c0 = lane & 15;
#pragma unroll
  for (int m = 0; m < 4; ++m)
#pragma unroll
    for (int n = 0; n < 4; ++n) {
      const int col = n0 + wn * 64 + n * 16 + c0;
#pragma unroll
      for (int r = 0; r < 4; ++r) {
        const int row = m0 + wm * 64 + m * 16 + r0 + r;
        Cp[(size_t)row * 1024 + col] = f2bf(acc[m][n][r] + zb[col]);
      }
    }
}

// ---------------- 128x256 GEMM, 3-slot 72KB LDS, 2 blocks/CU (R17/R19-verified) ----------------
template <int MODE>
__global__ __launch_bounds__(512, 4) void k_gemm256(
    const u16* __restrict__ A, int lda,
    const u16* __restrict__ BwA, const u16* __restrict__ BwB,
    const float* __restrict__ biasA, const float* __restrict__ biasB,
    void* __restrict__ CpA, void* __restrict__ CpB, int ldc,
    size_t thirdStride, const float* __restrict__ tab, int Nt, int NtA) {
  __shared__ u16 lds[3 * 12288];  // 72KB -> 2 blocks/CU

  const int tid = threadIdx.x, lane = tid & 63, wave = tid >> 6;
  const int wm = wave >> 2, wn = wave & 3;
  const int c0 = lane & 15, hi = lane >> 4;

  const int nwg = gridDim.x;
  const int qq = nwg >> 3, rr_ = nwg & 7;
  const int xcd = blockIdx.x & 7, sub = blockIdx.x >> 3;
  const int seq = (xcd < rr_ ? xcd * (qq + 1) : rr_ * (qq + 1) + (xcd - rr_) * qq) + sub;
  const int mt = seq / Nt, ntRaw = seq - mt * Nt;
  const int m0 = mt * 128;
  bool isV = false;
  int n0 = ntRaw * 256;
  const u16* Bbase;
  const float* bias;
  if (MODE == 0) {
    if (ntRaw >= NtA) {
      isV = true;
      n0 = (ntRaw - NtA) * 256;
      Bbase = BwB + (size_t)n0 * 1024;
      bias = biasB;
    } else {
      Bbase = BwA + (size_t)n0 * 1024;
      bias = biasA;
    }
  } else {
    Bbase = BwA + (size_t)n0 * 1024;
    bias = biasA;
  }
  const int aoff = (MODE == 1) ? (n0 & ~1023) : 0;

  const int Lb = tid >> 3, pc = tid & 7;
  const int lcl = pc ^ (Lb & 7);
  const int rsel = lcl >> 2;
  const int csel = (lcl & 3) * 8;
  const u16* aS = A + (size_t)(m0 + Lb + 64 * rsel) * lda + aoff + csel;
  const u16* bS0 = Bbase + (size_t)(Lb + 128 * rsel) * 1024 + csel;
  const u16* bS1 = Bbase + (size_t)(64 + Lb + 128 * rsel) * 1024 + csel;
  const uint32_t ldsW = wave * 512;

  auto stage = [&](int tt, u16* slot) {
    gload16(aS + tt * 32, slot + ldsW);
    gload16(bS0 + tt * 32, slot + 4096 + ldsW);
    gload16(bS1 + tt * 32, slot + 8192 + ldsW);
  };

  int aofr[4], bofr[4];
#pragma unroll
  for (int m = 0; m < 4; ++m)
    aofr[m] = (m * 16 + c0) * 64 + ((((wm << 2) | hi) ^ (c0 & 7)) * 8);
#pragma unroll
  for (int n = 0; n < 4; ++n)
    bofr[n] = 4096 + ((wn & 1) * 64 + n * 16 + c0) * 64 +
              (((((wn >> 1) << 2) | hi) ^ (c0 & 7)) * 8);

  u16* s0 = lds;
  u16* s1 = lds + 12288;
  u16* s2 = lds + 24576;

  stage(0, s0); stage(1, s1);
  asm volatile("s_waitcnt vmcnt(3)" ::: "memory");
  __builtin_amdgcn_s_barrier();
  __builtin_amdgcn_sched_barrier(0);

  f32x4 acc[4][4] = {};

  for (int t = 0; t < 32; ++t) {
    bf16x8 af[4], bfr[4];
#pragma unroll
    for (int n = 0; n < 4; ++n) bfr[n] = *(const bf16x8*)(s0 + bofr[n]);
#pragma unroll
    for (int m = 0; m < 4; ++m) af[m] = *(const bf16x8*)(s0 + aofr[m]);
    if (t + 2 < 32) stage(t + 2, s2);
    __builtin_amdgcn_s_setprio(1);
#pragma unroll
    for (int m = 0; m < 4; ++m)
#pragma unroll
      for (int n = 0; n < 4; ++n)
        acc[m][n] = __builtin_amdgcn_mfma_f32_16x16x32_bf16(af[m], bfr[n], acc[m][n], 0, 0, 0);
    __builtin_amdgcn_s_setprio(0);
    if (t < 31) {
      if (t < 30) asm volatile("s_waitcnt vmcnt(3)" ::: "memory");
      else        asm volatile("s_waitcnt vmcnt(0)" ::: "memory");
      __builtin_amdgcn_s_barrier();
      __builtin_amdgcn_sched_barrier(0);
      u16* tmp = s0; s0 = s1; s1 = s2; s2 = tmp;
    }
  }

  const int r0 = (lane >> 4) * 4;
#pragma unroll
  for (int m = 0; m < 4; ++m) {
#pragma unroll
    for (int n = 0; n < 4; ++n) {
      const int col = n0 + wn * 64 + n * 16 + c0;
      const float bv = bias[col];
      if (MODE == 0 && !isV) {
        const int pairI = (col & 1023) >> 1;
        const float sgn = (col & 1) ? 1.f : -1.f;
#pragma unroll
        for (int r = 0; r < 4; ++r) {
          const int row = m0 + wm * 64 + m * 16 + r0 + r;
          const float v = acc[m][n][r] + bv;
          const float p = __shfl_xor(v, 1);
          const float2 cs = ((const float2*)tab)[(row >> 8) * 512 + pairI];
          ((u16*)CpA)[(size_t)row * ldc + col] = f2bf(v * cs.x + sgn * p * cs.y);
        }
      } else if (MODE == 0 && isV) {
        const int h = (col >> 6) & 15, d = col & 63;
#pragma unroll
        for (int r = 0; r < 4; ++r) {
          const int row = m0 + wm * 64 + m * 16 + r0 + r;
          const int s = row >> 8, b = row & 255;
          ((u16*)CpB)[(((size_t)(b * NH + h) * S_LEN + s) * HDIM + d)] =
              f2bf(acc[m][n][r] + bv);
        }
      } else if (MODE == 1) {
        const int which = col >> 10, c = col & 1023;
        const int h = c >> 6, d = c & 63;
        const float sc = (which == 0) ? 0.125f : 1.0f;
#pragma unroll
        for (int r = 0; r < 4; ++r) {
          const int row = m0 + wm * 64 + m * 16 + r0 + r;
          const int s = row >> 8, b = row & 255;
          ((u16*)CpA)[(size_t)which * thirdStride +
                      (((size_t)(b * NH + h) * S_LEN + s) * HDIM + d)] =
              f2bf((acc[m][n][r] + bv) * sc);
        }
      } else {
#pragma unroll
        for (int r = 0; r < 4; ++r) {
          const int row = m0 + wm * 64 + m * 16 + r0 + r;
          ((float*)CpA)[(size_t)row * ldc + col] = acc[m][n][r] + bv;
        }
      }
    }
  }
}

// ---------------- attention v6 (R14/R16/R19-verified) ----------------
__global__ __launch_bounds__(512, 4) void k_attn(const u16* __restrict__ qkv2,
                                                 const float* __restrict__ maskP,
                                                 u16* __restrict__ O1) {
  __shared__ u16 Vt[66 * 128];     // Vt[d][s ^ ((d&7)<<3)]; row 64 = ones  16.5KB
  __shared__ u16 Pb[128 * 128];    // Pb[q][s ^ ((q&7)<<3)]; reused as Ob   32KB
  __shared__ float redS[128];

  const size_t TS = (size_t)MROWS * W_DIM;
  const int bh = blockIdx.x, b = bh >> 4, h = bh & 15;
  const int tid = threadIdx.x, lane = tid & 63, wave = tid >> 6;
  const int wm = wave >> 2;
  const int wn = wave & 3;
  const int c0 = lane & 15, hi = lane >> 4;

  const u16* Qg = qkv2 + (size_t)bh * (S_LEN * HDIM);
  const u16* Kg = Qg + TS;
  const u16* Vg = Qg + 2 * TS;

  float mk[4][2][4];
#pragma unroll
  for (int m = 0; m < 4; ++m)
#pragma unroll
    for (int n = 0; n < 2; ++n)
#pragma unroll
      for (int r = 0; r < 4; ++r)
        mk[m][n][r] = maskP[(wm * 64 + m * 16 + hi * 4 + r) * 128 + wn * 32 + n * 16 + c0];

  for (int idx = tid; idx < 1024; idx += 512) {
    const int s = idx >> 3, c = (idx & 7) * 8;
    uint4 vv = make_uint4(0, 0, 0, 0);
    if (s < S_LEN) vv = *(const uint4*)(Vg + (size_t)s * HDIM + c);
    u16 tmp[8];
    *(uint4*)tmp = vv;
#pragma unroll
    for (int j = 0; j < 8; ++j)
      Vt[(c + j) * 128 + (s ^ (j << 3))] = tmp[j];
  }
  if (tid < 128) Vt[64 * 128 + tid] = 0x3F80;   // ones row (d=64, swz=0)

  f32x4 acc[4][2] = {};
#pragma unroll
  for (int kk = 0; kk < 2; ++kk) {
    bf16x8 af[4], bfr[2];
#pragma unroll
    for (int m = 0; m < 4; ++m)
      af[m] = *(const bf16x8*)(Qg + (size_t)(wm * 64 + m * 16 + c0) * HDIM + kk * 32 + hi * 8);
#pragma unroll
    for (int n = 0; n < 2; ++n)
      bfr[n] = *(const bf16x8*)(Kg + (size_t)(wn * 32 + n * 16 + c0) * HDIM + kk * 32 + hi * 8);
#pragma unroll
    for (int m = 0; m < 4; ++m)
#pragma unroll
      for (int n = 0; n < 2; ++n)
        acc[m][n] = __builtin_amdgcn_mfma_f32_16x16x32_bf16(af[m], bfr[n], acc[m][n], 0, 0, 0);
  }

#pragma unroll
  for (int m = 0; m < 4; ++m) {
#pragma unroll
    for (int r = 0; r < 4; ++r) {
      const int row = wm * 64 + m * 16 + hi * 4 + r;
#pragma unroll
      for (int n = 0; n < 2; ++n) {
        const int col = wn * 32 + n * 16 + c0;
        const float e = __expf(acc[m][n][r] + mk[m][n][r]);
        Pb[row * 128 + (col ^ ((row & 7) << 3))] = f2bf(e);
      }
    }
  }
  __syncthreads();

  f32x4 o[4] = {};
  f32x4 osum[4] = {};
#pragma unroll
  for (int kk = 0; kk < 4; ++kk) {
    bf16x8 pa[4], vb, vbs;
#pragma unroll
    for (int m = 0; m < 4; ++m) {
      const int row = wm * 64 + m * 16 + c0;
      pa[m] = *(const bf16x8*)(Pb + row * 128 + ((kk * 32 + hi * 8) ^ ((row & 7) << 3)));
    }
    {
      const int d = wn * 16 + c0;
      vb = *(const bf16x8*)(Vt + d * 128 + ((kk * 32 + hi * 8) ^ ((d & 7) << 3)));
    }
    if (wn == 0)
      vbs = *(const bf16x8*)(Vt + 64 * 128 + (kk * 32 + hi * 8));  // broadcast
#pragma unroll
    for (int m = 0; m < 4; ++m)
      o[m] = __builtin_amdgcn_mfma_f32_16x16x32_bf16(pa[m], vb, o[m], 0, 0, 0);
    if (wn == 0) {
#pragma unroll
      for (int m = 0; m < 4; ++m)
        osum[m] = __builtin_amdgcn_mfma_f32_16x16x32_bf16(pa[m], vbs, osum[m], 0, 0, 0);
    }
  }

  if (wn == 0 && c0 == 0) {
#pragma unroll
    for (int m = 0; m < 4; ++m)
#pragma unroll
      for (int r = 0; r < 4; ++r)
        redS[wm * 64 + m * 16 + hi * 4 + r] = osum[m][r];
  }
  __syncthreads();

  u16* Ob = Pb;
#pragma unroll
  for (int m = 0; m < 4; ++m)
#pragma unroll
    for (int r = 0; r < 4; ++r) {
      const int row = wm * 64 + m * 16 + hi * 4 + r;
      const float iv = 1.0f / redS[row];
      Ob[row * 80 + wn * 16 + c0] = f2bf(o[m][r] * iv);
    }
  __syncthreads();

  if (tid < 4 * S_LEN) {
    const int row = tid >> 2, q = tid & 3;
    const u16* src = Ob + row * 80 + q * 16;
    uint4 a0 = *(const uint4*)(src);
    uint4 a1 = *(const uint4*)(src + 8);
    u16* dst = O1 + ((size_t)row * B_DIM + b) * W_DIM + h * HDIM + q * 16;
    *(uint4*)dst = a0;
    *(uint4*)(dst + 8) = a1;
  }
}

// ---------------- launcher ----------------
extern "C" void kernel_launch(void* const* d_in, const int* in_sizes, int n_in,
                              void* d_out, int out_size, void* d_ws, size_t ws_size,
                              hipStream_t stream) {
  (void)in_sizes; (void)n_in; (void)out_size; (void)ws_size;
  const float* tensor    = (const float*)d_in[0];
  const float* mask      = (const float*)d_in[1];
  const float* q_w       = (const float*)d_in[2];
  const float* q_b       = (const float*)d_in[3];
  const float* k_w       = (const float*)d_in[4];
  const float* k_b       = (const float*)d_in[5];
  const float* v_w       = (const float*)d_in[6];
  const float* v_b       = (const float*)d_in[7];
  const float* in_proj_w = (const float*)d_in[8];
  const float* in_proj_b = (const float*)d_in[9];
  const float* mha_w     = (const float*)d_in[10];
  const float* mha_b     = (const float*)d_in[11];
  const float* out_w     = (const float*)d_in[12];
  const float* out_b     = (const float*)d_in[13];

  char* ws = (char*)d_ws;
  size_t off = 0;
  auto alloc = [&](size_t bytes) {
    char* p = ws + off;
    off += (bytes + 255) & ~(size_t)255;
    return p;
  };

  const size_t TS = (size_t)MROWS * W_DIM;

  float* tab = (float*)alloc((size_t)S_LEN * 512 * 2 * sizeof(float));
  float* maskP = (float*)alloc((size_t)128 * 128 * sizeof(float));
  u16* Xbf   = (u16*)alloc(TS * 2);                          // reused as O1
  u16* qkv1  = (u16*)alloc((size_t)MROWS * 2048 * 2);        // q,k after GEMM1+rope
  u16* qkv2  = (u16*)alloc(TS * 3 * 2);                      // q,k,v head layout
  u16* WC1   = (u16*)alloc((size_t)2048 * 1024 * 2);         // [q_w;k_w] bf16
  u16* W2    = (u16*)alloc((size_t)3072 * 1024 * 2);         // in_proj bf16
  u16* WvT   = (u16*)alloc((size_t)1024 * 1024 * 2);
  u16* WmT   = (u16*)alloc((size_t)1024 * 1024 * 2);
  u16* WO    = (u16*)alloc((size_t)1024 * 1024 * 2);
  u16* WVf   = (u16*)alloc((size_t)1024 * 1024 * 2);         // Wv2 @ Wv
  u16* WFf   = (u16*)alloc((size_t)1024 * 1024 * 2);         // Wo @ Wm
  float* bc1 = (float*)alloc(2048 * sizeof(float));
  float* bvf = (float*)alloc(1024 * sizeof(float));
  float* bff = (float*)alloc(1024 * sizeof(float));
  float* zb  = (float*)alloc(1024 * sizeof(float));
  u16* O1 = Xbf;  // X dead after fused GEMM1v

  // ---- mega prep (one launch) ----
  k_prep<<<dim3(33806), 256, 0, stream>>>(
      tensor, Xbf, q_w, k_w, in_proj_w, out_w, WC1, W2, WO,
      v_w, WvT, mha_w, WmT, v_b, in_proj_b, bvf, mha_b, out_b, bff,
      tab, mask, maskP, q_b, k_b, bc1, zb);

  // ---- weight folds (both in one launch) ----
  k_gemmfold<<<dim3(8, 8, 2), 256, 0, stream>>>(
      W2 + (size_t)2048 * 1024, WvT, WVf, WO, WmT, WFf, zb);

  // ---- fused GEMM1+v: X @ [qk]^T -> qkv1(rope) ; X @ WVf^T -> v heads ----
  k_gemm256<0><<<dim3(194 * 12), 512, 0, stream>>>(
      Xbf, W_DIM, WC1, WVf, bc1, bvf, qkv1, qkv2 + 2 * TS, 2048, TS, tab, 12, 8);

  // ---- GEMM2 (block-diagonal): qkv1 @ [Wq2;Wk2]^T -> q,k heads (q scaled 1/8) ----
  k_gemm256<1><<<dim3(194 * 8), 512, 0, stream>>>(
      qkv1, 2048, W2, nullptr, in_proj_b, nullptr, qkv2, nullptr, 0, TS, nullptr, 8, 0);

  // ---- attention ----
  k_attn<<<dim3(B_DIM * NH), 512, 0, stream>>>(qkv2, maskP, O1);

  // ---- output (folded): O1 @ WFf^T + bff -> d_out (fp32) ----
  k_gemm256<2><<<dim3(194 * 4), 512, 0, stream>>>(
      O1, W_DIM, WFf, nullptr, bff, nullptr, d_out, nullptr, W_DIM, 0, nullptr, 4, 0);
}